// Round 9
// baseline (5826.484 us; speedup 1.0000x reference)
//
#include <hip/hip_runtime.h>
#include <hip/hip_bf16.h>
#include <stdint.h>

// GRU fused scan: B=128, T=512, I=H=512.
// 256 wgs x 192 threads (3 waves = gates r,z,n). wg (bgrp=id&7, ugrp=id>>3)
// owns batch rows [bgrp*16,+16) and hidden units [ugrp*16,+16).
// Sync protocol = round 6 (proven): h double-buffered bf16 in d_ws, written
// with agent-scope relaxed atomics; one monotonic flag word per wg
// (flag[wg]=t+1) stored after s_waitcnt vmcnt(0); consumers poll + ballot.
// NEW this round (traffic de-duplication, same protocol):
//  - Only the g0 wave polls the flags (was: all 3 waves -> 3x poll traffic).
//  - h[t] is loaded ONCE per wg by g0 as coalesced row loads (64 lanes x 8B
//    = 512B dense per instr), staged XOR-swizzled into a 16KB LDS tile, and
//    all 3 waves read their MFMA A-fragments via ds_read_b128 (2-way bank
//    alias = free). Was: each wave loaded the full 16KB slice itself via
//    8B sc0sc1 loads -> ~1536 IF transactions per wg-step; now ~128.
// x-side GEMM for t+1 stays at the end of iteration t (hides flag hop).

static constexpr int INPUT = 512;
static constexpr int HID   = 512;
static constexpr int NB    = 128;
static constexpr int TLEN  = 512;
static constexpr int BGRPS = 8;
static constexpr int UGRPS = 32;

typedef __attribute__((ext_vector_type(4))) float f32x4;
typedef __attribute__((ext_vector_type(8))) short s16x8;

static __device__ __forceinline__ unsigned short f2bf(float f) {
  unsigned u = __builtin_bit_cast(unsigned, f);
  u += 0x7FFFu + ((u >> 16) & 1u);   // RNE
  return (unsigned short)(u >> 16);
}

// 8 consecutive fp32 -> bf16x8 (RNE via packed convert)
static __device__ __forceinline__ s16x8 cvt8(const float* p) {
  f32x4 a = *(const f32x4*)p;
  f32x4 b = *(const f32x4*)(p + 4);
  unsigned r0, r1, r2, r3;
  asm("v_cvt_pk_bf16_f32 %0, %1, %2" : "=v"(r0) : "v"(a[0]), "v"(a[1]));
  asm("v_cvt_pk_bf16_f32 %0, %1, %2" : "=v"(r1) : "v"(a[2]), "v"(a[3]));
  asm("v_cvt_pk_bf16_f32 %0, %1, %2" : "=v"(r2) : "v"(b[0]), "v"(b[1]));
  asm("v_cvt_pk_bf16_f32 %0, %1, %2" : "=v"(r3) : "v"(b[2]), "v"(b[3]));
  union { unsigned u[4]; s16x8 s; } r;
  r.u[0] = r0; r.u[1] = r1; r.u[2] = r2; r.u[3] = r3;
  return r.s;
}

__global__ __launch_bounds__(192, 2) void gru_fused(
    const float* __restrict__ xs, const float* __restrict__ wih,
    const float* __restrict__ whh, const float* __restrict__ bias,
    const float* __restrict__ bias_n, float* __restrict__ out,
    unsigned short* __restrict__ hbuf, unsigned int* __restrict__ flags)
{
  const int wg   = blockIdx.x;
  const int bgrp = wg & 7;
  const int ugrp = wg >> 3;
  const int b0   = bgrp * 16;
  const int u0   = ugrp * 16;
  const int tid  = threadIdx.x;
  const int g    = tid >> 6;      // 0=r, 1=z, 2=n
  const int lane = tid & 63;
  const int ln   = lane & 15;     // unit / batch-row index within tile
  const int kg   = lane >> 4;     // k-octet group 0..3

  __shared__ unsigned short hlds[16 * 512];   // 16 KB h[t] tile (swizzled)
  __shared__ float xch[2][4][16][16];         // 8 KB gate exchange (dbuf)

  // ---- preload weight fragments into registers (one-time) ----
  const int rowW = g * HID + u0 + ln;
  s16x8 wa[16], wb[16];
#pragma unroll
  for (int ks = 0; ks < 16; ++ks) {
    const int k = ks * 32 + kg * 8;
    wa[ks] = cvt8(wih + (size_t)rowW * INPUT + k);
    wb[ks] = cvt8(whh + (size_t)rowW * HID + k);
  }
  const float bv = bias[rowW];
  const float bn = bias_n[u0 + ln];

  const float* xrow = xs + (size_t)(b0 + ln) * TLEN * INPUT + kg * 8;

  float hold[4] = {0.f, 0.f, 0.f, 0.f};

  // ---- prologue: input-side GEMM for t = 0 ----
  f32x4 acc_a = {bv, bv, bv, bv};
#pragma unroll
  for (int ks = 0; ks < 16; ++ks) {
    s16x8 xa = cvt8(xrow + ks * 32);
    acc_a = __builtin_amdgcn_mfma_f32_16x16x32_bf16(xa, wa[ks], acc_a, 0, 0, 0);
  }

  for (int t = 0; t < TLEN; ++t) {
    // ---- g0 wave: poll flags, then stage h[t] into LDS (coalesced) ----
    if (g == 0) {
      if (t > 0) {
        const unsigned* fp = &flags[bgrp * UGRPS + (lane & 31)];
        unsigned fv;
        do {
          fv = __hip_atomic_load(fp, __ATOMIC_RELAXED, __HIP_MEMORY_SCOPE_AGENT);
        } while (~__ballot(fv >= (unsigned)t));
        __builtin_amdgcn_sched_barrier(0);   // no hoist of h loads above poll
      }
      // load 16 rows x 1KB, lane covers bytes [lane*16, +16) of each row
      const unsigned long long* hs =
          (const unsigned long long*)(hbuf + (size_t)(t & 1) * (NB * HID)) +
          (size_t)b0 * 128;
#pragma unroll
      for (int r = 0; r < 16; ++r) {
        union { unsigned long long q[2]; s16x8 s; } u;
        u.q[0] = __hip_atomic_load(hs + r * 128 + 2 * lane,
                                   __ATOMIC_RELAXED, __HIP_MEMORY_SCOPE_AGENT);
        u.q[1] = __hip_atomic_load(hs + r * 128 + 2 * lane + 1,
                                   __ATOMIC_RELAXED, __HIP_MEMORY_SCOPE_AGENT);
        int byte = r * 1024 + ((lane * 16) ^ ((r & 7) << 4));
        *(s16x8*)((char*)hlds + byte) = u.s;
      }
    }
    __syncthreads();   // h tile visible to all 3 waves

    // ---- recurrent GEMM: hg = h[t] @ Whh^T (A-frags from LDS) ----
    f32x4 acc_b0 = {0.f, 0.f, 0.f, 0.f}, acc_b1 = {0.f, 0.f, 0.f, 0.f};
#pragma unroll
    for (int ks = 0; ks < 16; ks += 2) {
      int byte0 = ln * 1024 + ((ks * 64 + kg * 16) ^ ((ln & 7) << 4));
      int byte1 = ln * 1024 + (((ks + 1) * 64 + kg * 16) ^ ((ln & 7) << 4));
      s16x8 ha = *(const s16x8*)((const char*)hlds + byte0);
      s16x8 hbf = *(const s16x8*)((const char*)hlds + byte1);
      acc_b0 = __builtin_amdgcn_mfma_f32_16x16x32_bf16(ha,  wb[ks],     acc_b0, 0, 0, 0);
      acc_b1 = __builtin_amdgcn_mfma_f32_16x16x32_bf16(hbf, wb[ks + 1], acc_b1, 0, 0, 0);
    }
    f32x4 acc_b = acc_b0 + acc_b1;

    // ---- exchange gate pre-activations across the 3 waves (dbuf LDS) ----
    float (*xc)[16][16] = xch[t & 1];
    if (g == 0)      { f32x4 s = acc_a + acc_b; *(f32x4*)&xc[0][ln][kg * 4] = s; }
    else if (g == 1) { f32x4 s = acc_a + acc_b; *(f32x4*)&xc[1][ln][kg * 4] = s; }
    else             { *(f32x4*)&xc[2][ln][kg * 4] = acc_a;
                       *(f32x4*)&xc[3][ln][kg * 4] = acc_b; }
    __syncthreads();
    f32x4 Sr  = *(const f32x4*)&xc[0][ln][kg * 4];
    f32x4 Sz  = *(const f32x4*)&xc[1][ln][kg * 4];
    f32x4 Snx = *(const f32x4*)&xc[2][ln][kg * 4];
    f32x4 Snh = *(const f32x4*)&xc[3][ln][kg * 4];

    // ---- gate math (all waves redundantly; keeps h_old in regs everywhere) ----
    float hnew[4];
#pragma unroll
    for (int i = 0; i < 4; ++i) {
      float r = 1.f / (1.f + __expf(-Sr[i]));
      float z = 1.f / (1.f + __expf(-Sz[i]));
      float pre = Snx[i] + r * (Snh[i] + bn);
      float e = __expf(2.f * pre);
      float n = 1.f - 2.f / (e + 1.f);   // tanh, overflow-safe
      hnew[i] = n + z * (hold[i] - n);
      hold[i] = hnew[i];
    }

    if (t == TLEN - 1) {
      if (g == 0) {
#pragma unroll
        for (int i = 0; i < 4; ++i)
          out[(size_t)(b0 + kg * 4 + i) * HID + u0 + ln] = hnew[i];
      }
    } else {
      // ---- publish h[t+1], drain, set flag = t+1 ----
      if (g == 0) {
        unsigned short* hbn = hbuf + (size_t)((t + 1) & 1) * (NB * HID);
#pragma unroll
        for (int i = 0; i < 4; ++i) {
          int v  = (int)f2bf(hnew[i]);
          int o1 = __shfl_xor(v, 1);
          unsigned int p = (unsigned int)(v & 0xffff) | ((unsigned int)(o1 & 0xffff) << 16);
          unsigned int o2 = (unsigned int)__shfl_xor((int)p, 2);
          if ((ln & 3) == 0) {
            unsigned long long q = (unsigned long long)p | ((unsigned long long)o2 << 32);
            __hip_atomic_store(
                (unsigned long long*)(hbn + (size_t)(b0 + kg * 4 + i) * HID + u0 + ln),
                q, __ATOMIC_RELAXED, __HIP_MEMORY_SCOPE_AGENT);
          }
        }
        asm volatile("s_waitcnt vmcnt(0)" ::: "memory");  // h stores at IF
        if (tid == 0)
          __hip_atomic_store(&flags[bgrp * UGRPS + ugrp], (unsigned)(t + 1),
                             __ATOMIC_RELAXED, __HIP_MEMORY_SCOPE_AGENT);
      }

      // ---- input-side GEMM for step t+1 (hides flag propagation) ----
      acc_a = (f32x4){bv, bv, bv, bv};
      const float* xp = xrow + (size_t)(t + 1) * INPUT;
#pragma unroll
      for (int ks = 0; ks < 16; ++ks) {
        s16x8 xa = cvt8(xp + ks * 32);
        acc_a = __builtin_amdgcn_mfma_f32_16x16x32_bf16(xa, wa[ks], acc_a, 0, 0, 0);
      }
    }
  }
}

extern "C" void kernel_launch(void* const* d_in, const int* in_sizes, int n_in,
                              void* d_out, int out_size, void* d_ws, size_t ws_size,
                              hipStream_t stream) {
  const float* xs     = (const float*)d_in[0];
  const float* wih    = (const float*)d_in[1];
  const float* whh    = (const float*)d_in[2];
  const float* bias   = (const float*)d_in[3];
  const float* bias_n = (const float*)d_in[4];
  float* out = (float*)d_out;

  const size_t hbuf_bytes = (size_t)2 * NB * HID * sizeof(unsigned short); // 256 KB
  const size_t flg_bytes  = (size_t)BGRPS * UGRPS * sizeof(unsigned int);  // 1 KB
  unsigned short* hbuf  = (unsigned short*)d_ws;
  unsigned int*   flags = (unsigned int*)((char*)d_ws + hbuf_bytes);

  hipMemsetAsync(d_ws, 0, hbuf_bytes + flg_bytes, stream);

  gru_fused<<<dim3(BGRPS * UGRPS), dim3(192), 0, stream>>>(
      xs, wih, whh, bias, bias_n, out, hbuf, flags);
}